// Round 10
// baseline (53.575 us; speedup 1.0000x reference)
//
#include <hip/hip_runtime.h>
#include <hip/hip_fp16.h>

typedef _Float16 f16x2 __attribute__((ext_vector_type(2)));
typedef _Float16 f16x8 __attribute__((ext_vector_type(8)));
typedef float    f32x4 __attribute__((ext_vector_type(4)));

#define M_DIM   32
#define K_DIM   8192
#define N_DIM   28672
#define KWORDS  1024           // K/8 packed words per weight row
#define NKB     128            // K/64 scale blocks per row
#define NBLK_N  448            // N/64 n-blocks
#define NSPLIT  8
#define OUT_ELEMS (M_DIM * N_DIM)
#define X16_BYTES (KWORDS * M_DIM * 16)   // 512 KB fragment-layout x

__device__ __forceinline__ unsigned pkrtz(float a, float b) {
    return __builtin_bit_cast(unsigned, __builtin_amdgcn_cvt_pkrtz(a, b));
}

// x -> fragment-layout fp16: x16[w][m] = 8 fp16 of row m, pairs (k=8w+p, 8w+p+4)
// (identical k-permutation to the nibble unpack, so MFMA k-sums match)
__global__ __launch_bounds__(256) void x_transform(const float* __restrict__ x,
                                                   uint4* __restrict__ x16) {
    const int idx = blockIdx.x * 256 + threadIdx.x;   // w*32 + m
    const int w = idx >> 5, m = idx & 31;
    const float4* p = (const float4*)(x + (size_t)m * K_DIM + w * 8);
    float4 f0 = p[0], f1 = p[1];
    uint4 v = { pkrtz(f0.x, f1.x), pkrtz(f0.y, f1.y),
                pkrtz(f0.z, f1.z), pkrtz(f0.w, f1.w) };
    x16[idx] = v;
}

__global__ __launch_bounds__(256) void wql_init(const float* __restrict__ bias,
                                                float* __restrict__ out) {
    int n = blockIdx.x * 256 + threadIdx.x;
    int m = blockIdx.y;
    out[(size_t)m * N_DIM + n] = bias[n];
}

// 8 nibbles -> 8 dequantized fp16. Pair p = nibbles (p,p+4); 0x6400|q = 1024+q
// exact; cpk = -(1024+8+zq) exact; (f+cpk) exact small int; one rounding on *spk.
__device__ __forceinline__ f16x8 dq_word(unsigned W, f16x2 spk, f16x2 cpk) {
    union { f16x2 h[4]; f16x8 v; } r;
#pragma unroll
    for (int p = 0; p < 4; ++p) {
        unsigned raw = ((W >> (4 * p)) & 0x000F000Fu) | 0x64006400u;
        f16x2 f = __builtin_bit_cast(f16x2, raw);
        r.h[p] = (f + cpk) * spk;
    }
    return r.v;
}

// MAX-TLP design: 256 thr / 4 waves, n-tile 64 (16 rows per wave), all M=32.
// K-range 1024 (NSPLIT=8) as 4 chunks of 256k. LDS: 2 x 16KB double-buffer of
// x16 staged via global_load_lds (zero VALU staging). launch_bounds(256,5) ->
// VGPR<=102, 5 blocks/CU (LDS-capped) = 20 waves/CU, desynchronized across
// blocks. Latency hiding by TLP, scheduling left to the compiler.
template <bool ATOMIC>
__global__ __launch_bounds__(256, 5) void wql_main(
    const uint4* __restrict__ x16, const uint4* __restrict__ qw,
    const float* __restrict__ scales, const unsigned* __restrict__ qzeros,
    float* __restrict__ outp)
{
    __shared__ uint4 xs[2048];            // 2 bufs x [32 words][32 m] = 32 KB

    const int tid  = threadIdx.x;
    const int bid  = blockIdx.x;
    const int nblk = bid % NBLK_N;
    const int ks   = bid / NBLK_N;
    const int n0   = nblk * 64;

    const int wv   = tid >> 6;            // 0..3
    const int lane = tid & 63;
    const int g    = lane >> 4;           // k-group 0..3
    const int lr   = lane & 15;
    const int gh   = g >> 1;
    const int n_row = n0 + wv * 16 + lr;

    // per-row streams
    const uint4* qp4 = (const uint4*)(qw) + ((size_t)n_row * KWORDS + ks * 128) / 4;
    const f32x4* sp  = (const f32x4*)(scales + (size_t)n_row * NKB + ks * 16);
    const uint2  zw  = *(const uint2*)(qzeros + (size_t)n_row * 16 + ks * 2);
    const unsigned zr[2] = { zw.x, zw.y };

    // ---- stage chunk 0, hoist chunk-0 qweight/scales ----
    const uint4* gs0 = x16 + ((size_t)ks * 128) * 32;
#pragma unroll
    for (int i = 0; i < 4; ++i)
        __builtin_amdgcn_global_load_lds(
            (const __attribute__((address_space(1))) void*)(gs0 + tid + i * 256),
            (__attribute__((address_space(3))) void*)(&xs[tid + i * 256]),
            16, 0, 0);

    uint4 wq0 = qp4[g];                   // chunk 0, section 0 (words 4g..4g+3)
    uint4 wq1 = qp4[4 + g];               // chunk 0, section 1
    f32x4 sc  = sp[0];                    // chunk 0 scales (4 blocks)

    __syncthreads();

    f32x4 acc0 = {0.f, 0.f, 0.f, 0.f};
    f32x4 acc1 = {0.f, 0.f, 0.f, 0.f};

#pragma unroll
    for (int c = 0; c < 4; ++c) {
        const int buf = (c & 1) * 1024;
        // issue next chunk's stage + next qweight/scales (TLP covers latency)
        if (c < 3) {
            const uint4* gs = x16 + ((size_t)ks * 128 + (c + 1) * 32) * 32;
            const int nb = ((c + 1) & 1) * 1024;
#pragma unroll
            for (int i = 0; i < 4; ++i)
                __builtin_amdgcn_global_load_lds(
                    (const __attribute__((address_space(1))) void*)(gs + tid + i * 256),
                    (__attribute__((address_space(3))) void*)(&xs[nb + tid + i * 256]),
                    16, 0, 0);
        }
        uint4 nq0, nq1; f32x4 nsc;
        if (c < 3) {
            nq0 = qp4[(c + 1) * 8 + g];
            nq1 = qp4[(c + 1) * 8 + 4 + g];
            nsc = sp[c + 1];
        }

        // ---- compute chunk c: 2 sections x 4 j, 16 MFMA ----
#pragma unroll
        for (int s = 0; s < 2; ++s) {
            const int blk = c * 4 + 2 * s + gh;           // scale block in K-range
            const int zq  = (int)((zr[blk >> 3] >> (4 * (blk & 7))) & 0xF);
            const float sf = s ? (gh ? sc[3] : sc[2]) : (gh ? sc[1] : sc[0]);
            const _Float16 sh = (_Float16)sf;
            const _Float16 ch = (_Float16)(-(float)(1032 + zq));
            const f16x2 spk = { sh, sh };
            const f16x2 cpk = { ch, ch };
            const uint4 wq = s ? wq1 : wq0;
            const unsigned wa[4] = { wq.x, wq.y, wq.z, wq.w };
#pragma unroll
            for (int j = 0; j < 4; ++j) {
                const int wl = s * 16 + 4 * g + j;
                f16x8 b0 = __builtin_bit_cast(f16x8, xs[buf + wl * 32 + lr]);
                f16x8 b1 = __builtin_bit_cast(f16x8, xs[buf + wl * 32 + lr + 16]);
                f16x8 a  = dq_word(wa[j], spk, cpk);
                acc0 = __builtin_amdgcn_mfma_f32_16x16x32_f16(a, b0, acc0, 0, 0, 0);
                acc1 = __builtin_amdgcn_mfma_f32_16x16x32_f16(a, b1, acc1, 0, 0, 0);
            }
        }
        if (c < 3) { wq0 = nq0; wq1 = nq1; sc = nsc; }
        __syncthreads();
    }

    // C/D: col(m) = lane&15 -> acc0 m=lr, acc1 m=lr+16; n-within-16 = 4g+reg
    const size_t base = (size_t)lr * N_DIM + n0 + wv * 16 + 4 * g;
    if constexpr (ATOMIC) {
#pragma unroll
        for (int r = 0; r < 4; ++r) {
            atomicAdd(outp + base + r, acc0[r]);
            atomicAdd(outp + base + (size_t)16 * N_DIM + r, acc1[r]);
        }
    } else {
        float* dst = outp + (size_t)ks * OUT_ELEMS;
        *(f32x4*)(dst + base) = acc0;
        *(f32x4*)(dst + base + (size_t)16 * N_DIM) = acc1;
    }
}

// out = bias + sum of 8 split partials (partials L3-hot right after main)
__global__ __launch_bounds__(256) void wql_reduce(const float* __restrict__ ws,
                                                  const float* __restrict__ bias,
                                                  float* __restrict__ out) {
    const int i4 = (blockIdx.x * 256 + threadIdx.x) * 4;
    const int n  = i4 % N_DIM;
    f32x4 acc = *(const f32x4*)(bias + n);
#pragma unroll
    for (int s = 0; s < NSPLIT; ++s)
        acc += *(const f32x4*)(ws + (size_t)s * OUT_ELEMS + i4);
    *(f32x4*)(out + i4) = acc;
}

extern "C" void kernel_launch(void* const* d_in, const int* in_sizes, int n_in,
                              void* d_out, int out_size, void* d_ws, size_t ws_size,
                              hipStream_t stream) {
    const float*    x      = (const float*)d_in[0];
    const uint4*    qwght  = (const uint4*)d_in[1];
    const float*    scales = (const float*)d_in[2];
    const unsigned* qzeros = (const unsigned*)d_in[3];
    const float*    bias   = (const float*)d_in[4];
    float* out = (float*)d_out;

    uint4* x16 = (uint4*)d_ws;
    float* part = (float*)((char*)d_ws + X16_BYTES);
    const size_t need = X16_BYTES + (size_t)NSPLIT * OUT_ELEMS * sizeof(float);

    x_transform<<<dim3(KWORDS * M_DIM / 256), 256, 0, stream>>>(x, x16);
    if (ws_size >= need) {
        wql_main<false><<<dim3(NBLK_N * NSPLIT), 256, 0, stream>>>(
            x16, qwght, scales, qzeros, part);
        wql_reduce<<<dim3(OUT_ELEMS / 1024), 256, 0, stream>>>(
            part, bias, out);
    } else {
        wql_init<<<dim3(N_DIM / 256, M_DIM), 256, 0, stream>>>(bias, out);
        wql_main<true><<<dim3(NBLK_N * NSPLIT), 256, 0, stream>>>(
            x16, qwght, scales, qzeros, out);
    }
}

// Round 11
// 50.506 us; speedup vs baseline: 1.0608x; 1.0608x over previous
//
#include <hip/hip_runtime.h>
#include <hip/hip_fp16.h>

typedef _Float16 f16x2 __attribute__((ext_vector_type(2)));
typedef _Float16 f16x8 __attribute__((ext_vector_type(8)));
typedef float    f32x4 __attribute__((ext_vector_type(4)));

#define M_DIM   32
#define K_DIM   8192
#define N_DIM   28672
#define KWORDS  1024           // K/8 packed words per weight row
#define NKB     128            // K/64 scale blocks per row
#define NBLKN   56             // N/512 n-blocks
#define NSPLIT  8
#define OUT_ELEMS (M_DIM * N_DIM)
#define X16_BYTES (KWORDS * M_DIM * 16)   // 512 KB fragment-layout x

__device__ __forceinline__ unsigned pkrtz(float a, float b) {
    return __builtin_bit_cast(unsigned, __builtin_amdgcn_cvt_pkrtz(a, b));
}

// x -> fragment-layout fp16: x16[w][m] = 8 fp16 of row m, pairs (k=8w+p, 8w+p+4)
// (identical k-permutation to the nibble unpack, so MFMA k-sums match)
__global__ __launch_bounds__(256) void x_transform(const float* __restrict__ x,
                                                   uint4* __restrict__ x16) {
    const int idx = blockIdx.x * 256 + threadIdx.x;   // w*32 + m
    const int w = idx >> 5, m = idx & 31;
    const float4* p = (const float4*)(x + (size_t)m * K_DIM + w * 8);
    float4 f0 = p[0], f1 = p[1];
    uint4 v = { pkrtz(f0.x, f1.x), pkrtz(f0.y, f1.y),
                pkrtz(f0.z, f1.z), pkrtz(f0.w, f1.w) };
    x16[idx] = v;
}

__global__ __launch_bounds__(256) void wql_init(const float* __restrict__ bias,
                                                float* __restrict__ out) {
    int n = blockIdx.x * 256 + threadIdx.x;
    int m = blockIdx.y;
    out[(size_t)m * N_DIM + n] = bias[n];
}

// 8 nibbles -> 8 dequantized fp16. Pair p = nibbles (p,p+4); 0x6400|q = 1024+q
// exact; cpk = -(1024+8+zq) exact; (f+cpk) exact small int; one rounding on *spk.
__device__ __forceinline__ f16x8 dq_word(unsigned W, f16x2 spk, f16x2 cpk) {
    union { f16x2 h[4]; f16x8 v; } r;
#pragma unroll
    for (int p = 0; p < 4; ++p) {
        unsigned raw = ((W >> (4 * p)) & 0x000F000Fu) | 0x64006400u;
        f16x2 f = __builtin_bit_cast(f16x2, raw);
        r.h[p] = (f + cpk) * spk;
    }
    return r.v;
}

// ONE-BARRIER design: 512 thr / 8 waves. Block owns K-chunk 1024 (NSPLIT=8)
// and n-range 512. Stage the full x16 K-slab (64 KB) via global_load_lds,
// ONE __syncthreads, then a barrier-free n-loop (2 iters x 256 n): LDS is
// read-only, waves free-run, compiler pipelines qweight/scale loads across
// sections with no drain points. Wave = 32 n-rows (2 sub-tiles share B-frags).
template <bool ATOMIC>
__global__ __launch_bounds__(512, 2) void wql_main(
    const uint4* __restrict__ x16, const unsigned* __restrict__ qw,
    const float* __restrict__ scales, const unsigned* __restrict__ qzeros,
    float* __restrict__ outp)
{
    __shared__ uint4 xs[4096];            // [128 words][32 m] = 64 KB, whole chunk

    const int tid  = threadIdx.x;
    const int bid  = blockIdx.x;
    const int nblk = bid % NBLKN;
    const int ks   = bid / NBLKN;
    const int n0   = nblk * 512;

    const int wv   = tid >> 6;            // 0..7
    const int lane = tid & 63;
    const int g    = lane >> 4;           // k-group 0..3
    const int lr   = lane & 15;
    const int gh   = g >> 1;

    // ---- stage whole x16 chunk -> LDS (zero-VALU), single barrier ----
    {
        const uint4* gs = x16 + (size_t)ks * 4096;
#pragma unroll
        for (int i = 0; i < 8; ++i)
            __builtin_amdgcn_global_load_lds(
                (const __attribute__((address_space(1))) void*)(gs + tid + i * 512),
                (__attribute__((address_space(3))) void*)(&xs[tid + i * 512]),
                16, 0, 0);
    }
    __syncthreads();                       // the ONLY barrier

#pragma unroll
    for (int it = 0; it < 2; ++it) {
        const int nb = n0 + it * 256 + wv * 32;
        const int r0 = nb + lr;            // sub-tile 0 n-row
        const int r1 = r0 + 16;            // sub-tile 1 n-row

        const uint4* qp0 = (const uint4*)(qw + (size_t)r0 * KWORDS + ks * 128);
        const uint4* qp1 = (const uint4*)(qw + (size_t)r1 * KWORDS + ks * 128);
        const f32x4* sv0 = (const f32x4*)(scales + (size_t)r0 * NKB + ks * 16);
        const f32x4* sv1 = (const f32x4*)(scales + (size_t)r1 * NKB + ks * 16);
        const uint2  zw0 = *(const uint2*)(qzeros + (size_t)r0 * 16 + ks * 2);
        const uint2  zw1 = *(const uint2*)(qzeros + (size_t)r1 * 16 + ks * 2);

        f32x4 s0[4], s1[4];
#pragma unroll
        for (int i = 0; i < 4; ++i) { s0[i] = sv0[i]; s1[i] = sv1[i]; }

        f32x4 acc00 = {0,0,0,0}, acc01 = {0,0,0,0};
        f32x4 acc10 = {0,0,0,0}, acc11 = {0,0,0,0};

#pragma unroll
        for (int s = 0; s < 8; ++s) {      // 8 sections x 16 words (128 k each)
            const uint4 w0 = qp0[s * 4 + g];
            const uint4 w1 = qp1[s * 4 + g];
            // scale block in chunk = 2s+gh; zeros word = s>>2, nibble (2s&7)+gh
            const unsigned zl0 = (s < 4) ? zw0.x : zw0.y;
            const unsigned zl1 = (s < 4) ? zw1.x : zw1.y;
            const int sh4 = 4 * ((2 * s) & 7) + 4 * gh;
            const int zq0 = (int)((zl0 >> sh4) & 0xF);
            const int zq1 = (int)((zl1 >> sh4) & 0xF);
            const float sf0 = gh ? s0[s >> 1][2 * (s & 1) + 1] : s0[s >> 1][2 * (s & 1)];
            const float sf1 = gh ? s1[s >> 1][2 * (s & 1) + 1] : s1[s >> 1][2 * (s & 1)];
            const _Float16 h0 = (_Float16)sf0, h1 = (_Float16)sf1;
            const f16x2 spk0 = { h0, h0 }, spk1 = { h1, h1 };
            const _Float16 c0 = (_Float16)(-(float)(1032 + zq0));
            const _Float16 c1 = (_Float16)(-(float)(1032 + zq1));
            const f16x2 cpk0 = { c0, c0 }, cpk1 = { c1, c1 };
            const unsigned wa0[4] = { w0.x, w0.y, w0.z, w0.w };
            const unsigned wa1[4] = { w1.x, w1.y, w1.z, w1.w };
#pragma unroll
            for (int j = 0; j < 4; ++j) {
                const int wl = s * 16 + 4 * g + j;
                f16x8 b0 = __builtin_bit_cast(f16x8, xs[wl * 32 + lr]);
                f16x8 b1 = __builtin_bit_cast(f16x8, xs[wl * 32 + lr + 16]);
                f16x8 a0 = dq_word(wa0[j], spk0, cpk0);
                f16x8 a1 = dq_word(wa1[j], spk1, cpk1);
                acc00 = __builtin_amdgcn_mfma_f32_16x16x32_f16(a0, b0, acc00, 0,0,0);
                acc01 = __builtin_amdgcn_mfma_f32_16x16x32_f16(a0, b1, acc01, 0,0,0);
                acc10 = __builtin_amdgcn_mfma_f32_16x16x32_f16(a1, b0, acc10, 0,0,0);
                acc11 = __builtin_amdgcn_mfma_f32_16x16x32_f16(a1, b1, acc11, 0,0,0);
            }
        }

        // C/D: col(m)=lane&15, n-within-16 = 4*(lane>>4)+reg (validated R1..R10)
        const size_t base = (size_t)lr * N_DIM + nb + 4 * g;
        if constexpr (ATOMIC) {
#pragma unroll
            for (int r = 0; r < 4; ++r) {
                atomicAdd(outp + base + r, acc00[r]);
                atomicAdd(outp + base + 16 + r, acc10[r]);
                atomicAdd(outp + base + (size_t)16 * N_DIM + r, acc01[r]);
                atomicAdd(outp + base + (size_t)16 * N_DIM + 16 + r, acc11[r]);
            }
        } else {
            float* dst = outp + (size_t)ks * OUT_ELEMS;
            *(f32x4*)(dst + base) = acc00;
            *(f32x4*)(dst + base + 16) = acc10;
            *(f32x4*)(dst + (size_t)16 * N_DIM + base) = acc01;
            *(f32x4*)(dst + (size_t)16 * N_DIM + base + 16) = acc11;
        }
    }
}

// out = bias + sum of 8 split partials (partials L2/L3-hot right after main)
__global__ __launch_bounds__(256) void wql_reduce(const float* __restrict__ ws,
                                                  const float* __restrict__ bias,
                                                  float* __restrict__ out) {
    const int i4 = (blockIdx.x * 256 + threadIdx.x) * 4;
    const int n  = i4 % N_DIM;
    f32x4 acc = *(const f32x4*)(bias + n);
#pragma unroll
    for (int s = 0; s < NSPLIT; ++s)
        acc += *(const f32x4*)(ws + (size_t)s * OUT_ELEMS + i4);
    *(f32x4*)(out + i4) = acc;
}

extern "C" void kernel_launch(void* const* d_in, const int* in_sizes, int n_in,
                              void* d_out, int out_size, void* d_ws, size_t ws_size,
                              hipStream_t stream) {
    const float*    x      = (const float*)d_in[0];
    const unsigned* qwght  = (const unsigned*)d_in[1];
    const float*    scales = (const float*)d_in[2];
    const unsigned* qzeros = (const unsigned*)d_in[3];
    const float*    bias   = (const float*)d_in[4];
    float* out = (float*)d_out;

    uint4* x16 = (uint4*)d_ws;
    float* part = (float*)((char*)d_ws + X16_BYTES);
    const size_t need = X16_BYTES + (size_t)NSPLIT * OUT_ELEMS * sizeof(float);

    x_transform<<<dim3(KWORDS * M_DIM / 256), 256, 0, stream>>>(x, (uint4*)x16);
    if (ws_size >= need) {
        wql_main<false><<<dim3(NBLKN * NSPLIT), 512, 0, stream>>>(
            x16, qwght, scales, qzeros, part);
        wql_reduce<<<dim3(OUT_ELEMS / 1024), 256, 0, stream>>>(
            part, bias, out);
    } else {
        wql_init<<<dim3(N_DIM / 256, M_DIM), 256, 0, stream>>>(bias, out);
        wql_main<true><<<dim3(NBLKN * NSPLIT), 512, 0, stream>>>(
            x16, qwght, scales, qzeros, out);
    }
}